// Round 5
// baseline (51.903 us; speedup 1.0000x reference)
//
#include <hip/hip_runtime.h>

#define EPSF 1e-6f
typedef float f4 __attribute__((ext_vector_type(4)));

// K1: one 64-lane wave per TWO (b,c) planes; 32 lanes per plane.
// Lane-in-half l: c = l&7 (4-col chunk), g = l>>3 (row mod 4).
// Iteration t in 0..7 covers row 4t+g, cols [4c,4c+4): float4 idx t*32+l.
// All shuffles use xor offsets < 32 or half-local gathers, so each DS op
// serves both planes simultaneously (21 DS ops/plane vs 50 in round 4).
// Outputs: rm[p*16 + r] (14 region maxes) and per-block SS partial
// sspart[bid*16 + r] (plain stores; atomics were a 10us regression in r3).
__global__ __launch_bounds__(256) void k1_regions(
    const float* __restrict__ x, float* __restrict__ rm,
    float* __restrict__ sspart) {
  const int lane = threadIdx.x & 63;
  const int wv = threadIdx.x >> 6;
  const int h = lane >> 5;      // which plane of this wave's pair
  const int l = lane & 31;      // lane within half
  const int pi = wv * 2 + h;    // plane index within block (0..7)
  const int p = blockIdx.x * 8 + pi;  // global plane, 0..65535
  const f4* xp = reinterpret_cast<const f4*>(x) + (size_t)p * 256;

  const int c = l & 7;
  const int g = l >> 3;  // 0..3; lane covers rows {g, 4+g, ..., 28+g}
  const bool c5 = (c == 5), c2 = (c == 2), eact = c5 || c2;

  // 8 outstanding non-temporal 16B loads (streaming, zero reuse).
  f4 v[8];
#pragma unroll
  for (int t = 0; t < 8; ++t)
    v[t] = __builtin_nontemporal_load(&xp[t * 32 + l]);

  float m[8], e[8];
#pragma unroll
  for (int t = 0; t < 8; ++t) {
    m[t] = fmaxf(fmaxf(v[t][0], v[t][1]), fmaxf(v[t][2], v[t][3]));
    e[t] = eact ? (c5 ? v[t][0] : v[t][3]) : -INFINITY;  // col 20 / col 11
  }

  // Row-band values (row = 4t+g):
  float vals[8];
  vals[0] = fmaxf(m[0], m[1]);  // rows [0,8)
  vals[1] = fmaxf(m[2], m[3]);  // rows [8,16)
  vals[2] = fmaxf(m[4], m[5]);  // rows [16,24)
  vals[3] = fmaxf(m[6], m[7]);  // rows [24,32)
  vals[4] = fmaxf(m[4], (g == 0) ? m[5] : -INFINITY);  // rows 16..20
  vals[5] = fmaxf(m[3], (g == 3) ? m[2] : -INFINITY);  // rows 11..15
  float E1 = fmaxf(fmaxf(fmaxf(e[0], e[1]), fmaxf(e[2], e[3])), e[4]);
  vals[6] = fmaxf(E1, (g == 0) ? e[5] : -INFINITY);    // edge col, rows [0,21)
  float E2 = fmaxf(fmaxf(fmaxf(e[3], e[4]), fmaxf(e[5], e[6])), e[7]);
  vals[7] = fmaxf(E2, (g == 3) ? e[2] : -INFINITY);    // edge col, rows [11,32)

  // g-bit allreduce within each 32-half (xor 8, 16).
#pragma unroll
  for (int off = 8; off <= 16; off <<= 1) {
#pragma unroll
    for (int i = 0; i < 8; ++i)
      vals[i] = fmaxf(vals[i], __shfl_xor(vals[i], off, 64));
  }

  // Per-chunk row-band composites.
  const float M2a = fmaxf(fmaxf(vals[0], vals[1]), vals[4]);  // rows [0,21)
  const float M2b = fmaxf(vals[5], fmaxf(vals[2], vals[3]));  // rows [11,32)
  const float M3a = fmaxf(vals[0], vals[1]);                  // rows [0,16)
  const float M3b = fmaxf(vals[1], vals[2]);                  // rows [8,24)
  const float M3c = fmaxf(vals[2], vals[3]);                  // rows [16,32)
  const float Ea = vals[6], Eb = vals[7];

  // Scale-2 regions: masked butterflies over c bits (xor 1,2,4 — half-local).
  float a1 = (c <= 4) ? M2a : (c5 ? Ea : -INFINITY);  // cols [0,21)
  float a2 = (c >= 3) ? M2a : (c2 ? Ea : -INFINITY);  // cols [11,32)
  float a3 = (c <= 4) ? M2b : (c5 ? Eb : -INFINITY);
  float a4 = (c >= 3) ? M2b : (c2 ? Eb : -INFINITY);
#pragma unroll
  for (int off = 1; off <= 4; off <<= 1) {
    a1 = fmaxf(a1, __shfl_xor(a1, off, 64));
    a2 = fmaxf(a2, __shfl_xor(a2, off, 64));
    a3 = fmaxf(a3, __shfl_xor(a3, off, 64));
    a4 = fmaxf(a4, __shfl_xor(a4, off, 64));
  }

  // Scale-3: pair (xor1) -> quad (xor2) + mid (xor6: pair23<->pair45).
  const float pA = fmaxf(M3a, __shfl_xor(M3a, 1, 64));
  const float pB = fmaxf(M3b, __shfl_xor(M3b, 1, 64));
  const float pC = fmaxf(M3c, __shfl_xor(M3c, 1, 64));
  const float qA = fmaxf(pA, __shfl_xor(pA, 2, 64));
  const float qB = fmaxf(pB, __shfl_xor(pB, 2, 64));
  const float qC = fmaxf(pC, __shfl_xor(pC, 2, 64));
  const float mA = fmaxf(pA, __shfl_xor(pA, 6, 64));  // valid lanes c=2..5
  const float mB = fmaxf(pB, __shfl_xor(pB, 6, 64));
  const float mC = fmaxf(pC, __shfl_xor(pC, 6, 64));

  // Global region.
  const float t0 = fmaxf(qA, qC);
  const float r0 = fmaxf(t0, __shfl_xor(t0, 4, 64));

  // Gathers from half-local source lanes.
  const int hb = lane & 32;
  const float b5 = __shfl(qA, hb + 0, 64);   // M3a quad0 -> lane 5
  const float b6 = __shfl(mA, hb + 2, 64);   // M3a mid   -> lane 6
  const float b9 = __shfl(mB, hb + 2, 64);   // M3b mid   -> lane 9
  const float b10 = __shfl(qB, hb + 4, 64);  // M3b quad1 -> lane 10

  // Destination lane l (within half) holds region r_l:
  //  0:r0  1..4:a1..a4  5:3a-q0  6:3a-mid  7:3a-q1(c7 local)
  //  8:3b-q0(c0 local)  9:3b-mid  10:3b-q1  11:3c-q0(c3)  12:3c-mid(c4)
  //  13:3c-q1(c5)
  float outv = r0;
  outv = (l == 1) ? a1 : outv;
  outv = (l == 2) ? a2 : outv;
  outv = (l == 3) ? a3 : outv;
  outv = (l == 4) ? a4 : outv;
  outv = (l == 5) ? b5 : outv;
  outv = (l == 6) ? b6 : outv;
  outv = (l == 7) ? qA : outv;
  outv = (l == 8) ? qB : outv;
  outv = (l == 9) ? b9 : outv;
  outv = (l == 10) ? b10 : outv;
  outv = (l == 11) ? qC : outv;
  outv = (l == 12) ? mC : outv;
  outv = (l == 13) ? qC : outv;

  if (l < 14) rm[(size_t)p * 16 + l] = outv;

  // Per-block SS partial over this block's 8 planes (conflict-free layout:
  // wave wv writes banks l (pi even) and 16+l (pi odd)).
  __shared__ float red[8][16];
  if (l < 14) red[pi][l] = outv * outv;
  __syncthreads();
  if (wv == 0 && lane < 14) {
    float s = red[0][lane];
#pragma unroll
    for (int k = 1; k < 8; ++k) s += red[k][lane];
    sspart[blockIdx.x * 16 + lane] = s;
  }
}

// K2: 256 blocks (b = bid>>3, slice = bid&7). Each block redundantly reduces
// its batch's 256 SS partials (16KB, LLC-hot) -> ninv[14] in LDS -> apply.
__global__ __launch_bounds__(256) void k2_apply(
    const float* __restrict__ rm, const float* __restrict__ sspart,
    float* __restrict__ out) {
  const int bid = blockIdx.x;
  const int tid = threadIdx.x;
  const int lane = tid & 63, wv = tid >> 6;
  const int b = bid >> 3;

  // Thread t reads partial (b*256 + t): entries 14,15 are poison, never used.
  const float4* e =
      reinterpret_cast<const float4*>(sspart + ((size_t)b * 256 + tid) * 16);
  const float4 u0 = e[0], u1 = e[1], u2 = e[2], u3 = e[3];
  float ss[14] = {u0.x, u0.y, u0.z, u0.w, u1.x, u1.y, u1.z,
                  u1.w, u2.x, u2.y, u2.z, u2.w, u3.x, u3.y};

#pragma unroll
  for (int off = 32; off >= 1; off >>= 1) {
#pragma unroll
    for (int i = 0; i < 14; ++i) ss[i] += __shfl_xor(ss[i], off, 64);
  }

  __shared__ float red[4][14];
  __shared__ float ninv[14];
  if (lane == 0) {
#pragma unroll
    for (int i = 0; i < 14; ++i) red[wv][i] = ss[i];
  }
  __syncthreads();
  if (tid < 14) {
    const float s = red[0][tid] + red[1][tid] + red[2][tid] + red[3][tid];
    const float w = (tid == 0) ? 2.0f : 1.0f;  // global region == l=1 region
    ninv[tid] = w / (sqrtf(s) + EPSF);
  }
  __syncthreads();

  const int p = b * 2048 + (bid & 7) * 256 + tid;
  const float4* q = reinterpret_cast<const float4*>(rm) + (size_t)p * 4;
  const float4 q0 = q[0], q1 = q[1], q2 = q[2], q3 = q[3];
  float o = ninv[0] * q0.x + ninv[1] * q0.y + ninv[2] * q0.z + ninv[3] * q0.w;
  o += ninv[4] * q1.x + ninv[5] * q1.y + ninv[6] * q1.z + ninv[7] * q1.w;
  o += ninv[8] * q2.x + ninv[9] * q2.y + ninv[10] * q2.z + ninv[11] * q2.w;
  o += ninv[12] * q3.x + ninv[13] * q3.y;
  out[p] = o;
}

extern "C" void kernel_launch(void* const* d_in, const int* in_sizes, int n_in,
                              void* d_out, int out_size, void* d_ws, size_t ws_size,
                              hipStream_t stream) {
  const float* x = (const float*)d_in[0];
  float* out = (float*)d_out;

  const size_t RM_BYTES = (size_t)65536 * 16 * 4;    // 4.19 MB
  float* rm = (float*)d_ws;
  float* sspart = (float*)((char*)d_ws + RM_BYTES);  // 8192*16 floats = 512 KB

  k1_regions<<<8192, 256, 0, stream>>>(x, rm, sspart);
  k2_apply<<<256, 256, 0, stream>>>(rm, sspart, out);
}